// Round 1
// baseline (32.281 us; speedup 1.0000x reference)
//
#include <hip/hip_runtime.h>
#include <hip/hip_bf16.h>
#include <math.h>

#define SRATE 48000.0
#define SEGSZ 960
#define NHARM 8
#define LFRM 250
#define LWAVE (LFRM * SEGSZ)   // 240000
#define CCH 256

// ---------------------------------------------------------------------------
// Kernel 1: per-frame 1x1 convs -> f0[n][i], magbar[n][i] (= mean_h mag_h)
// block = 256 threads = 4 waves; each wave handles 64 channels, LDS-reduced.
// grid = (N, 4) ; i = blockIdx.y*64 + lane
// ---------------------------------------------------------------------------
__global__ __launch_bounds__(256) void k_frames(
        const float* __restrict__ x,
        const float* __restrict__ w_mag, const float* __restrict__ b_mag,
        const float* __restrict__ w_oct, const float* __restrict__ b_oct,
        float* __restrict__ f0, float* __restrict__ magbar) {
    __shared__ float sw[(NHARM + 1) * CCH];     // w_mag[8][256] then w_oct[256]
    __shared__ float sred[NHARM + 1][4][64];
    int tid  = threadIdx.x;
    int lane = tid & 63;
    int wv   = tid >> 6;
    for (int idx = tid; idx < NHARM * CCH; idx += 256) sw[idx] = w_mag[idx];
    for (int idx = tid; idx < CCH; idx += 256) sw[NHARM * CCH + idx] = w_oct[idx];
    __syncthreads();

    int n = blockIdx.x;
    int i = blockIdx.y * 64 + lane;
    bool act = (i < LFRM);
    int ii = act ? i : (LFRM - 1);
    const float* xp = x + (size_t)n * CCH * LFRM + ii;

    float oct = 0.f;
    float mh[NHARM];
#pragma unroll
    for (int h = 0; h < NHARM; ++h) mh[h] = 0.f;

    int c0 = wv * 64;
#pragma unroll 8
    for (int cc = 0; cc < 64; ++cc) {
        int c = c0 + cc;
        float xv = xp[c * LFRM];
        oct = fmaf(sw[NHARM * CCH + c], xv, oct);
#pragma unroll
        for (int h = 0; h < NHARM; ++h) mh[h] = fmaf(sw[h * CCH + c], xv, mh[h]);
    }
    sred[0][wv][lane] = oct;
#pragma unroll
    for (int h = 0; h < NHARM; ++h) sred[1 + h][wv][lane] = mh[h];
    __syncthreads();

    if (tid < 64 && act) {
        float o = sred[0][0][lane] + sred[0][1][lane] + sred[0][2][lane] + sred[0][3][lane];
        o += b_oct[0];
        float f0v = 220.0f * exp2f(o);
        float ms = 0.f;
#pragma unroll
        for (int h = 0; h < NHARM; ++h) {
            float mv = sred[1 + h][0][lane] + sred[1 + h][1][lane]
                     + sred[1 + h][2][lane] + sred[1 + h][3][lane];
            ms += expf(fminf(mv + b_mag[h], 6.0f));
        }
        f0[n * LFRM + i]     = f0v;
        magbar[n * LFRM + i] = ms * (1.0f / NHARM);
    }
}

// ---------------------------------------------------------------------------
// Kernel 2: per-batch prefix of region sums, in f64. One wave per n.
// S[k] = 480*(f0[k]+f0[k+1])/SR  (k=0..248)
// P[k] = head + sum_{k'<k} S[k'],  head = 480*f0[0]/SR,  k=0..249
// ---------------------------------------------------------------------------
__global__ __launch_bounds__(64) void k_scan(const float* __restrict__ f0,
                                             double* __restrict__ P) {
    int n = blockIdx.x;
    int lane = threadIdx.x;           // 0..63, lane owns k = 4*lane .. 4*lane+3
    const float* f = f0 + n * LFRM;

    double S[4];
    double local = 0.0;
#pragma unroll
    for (int m = 0; m < 4; ++m) {
        int k = 4 * lane + m;
        double s = 0.0;
        if (k < LFRM - 1)
            s = 480.0 * ((double)f[k] + (double)f[k + 1]) * (1.0 / SRATE);
        S[m] = s;
        local += s;
    }
    double incl = local;
    for (int off = 1; off < 64; off <<= 1) {
        double up = __shfl_up(incl, off, 64);
        if (lane >= off) incl += up;
    }
    double run = (incl - local) + 480.0 * (double)f[0] * (1.0 / SRATE);
#pragma unroll
    for (int m = 0; m < 4; ++m) {
        int k = 4 * lane + m;
        if (k < LFRM) P[n * LFRM + k] = run;
        run += S[m];
    }
}

// ---------------------------------------------------------------------------
// Kernel 3: per-sample phase (f64, exact), sin via v_sin_f32 (revolutions),
// mag lerp, store. One sample per thread.
// ---------------------------------------------------------------------------
__global__ __launch_bounds__(256) void k_wave(
        const float* __restrict__ f0, const float* __restrict__ magbar,
        const double* __restrict__ P, const float* __restrict__ phi,
        float* __restrict__ out) {
    int n = blockIdx.y;
    int l = blockIdx.x * blockDim.x + threadIdx.x;
    if (l >= LWAVE) return;

    const float* f  = f0 + n * LFRM;
    const float* mb = magbar + n * LFRM;
    double ph = (double)phi[n];
    double t;
    float mag;

    if (l < SEGSZ / 2) {                         // head: 480 samples of f0[0]
        int m = l + 1;
        t = ph + (double)m * (double)f[0] * (1.0 / SRATE);
        mag = mb[0];
    } else if (l >= LWAVE - SEGSZ / 2) {         // tail: 480 samples of f0[249]
        int m = l - (LWAVE - SEGSZ / 2) + 1;
        t = ph + P[n * LFRM + (LFRM - 1)]
              + (double)m * (double)f[LFRM - 1] * (1.0 / SRATE);
        mag = mb[LFRM - 1];
    } else {                                     // region k, sample j
        int lr = l - SEGSZ / 2;
        int k = lr / SEGSZ;
        int j = lr - k * SEGSZ;
        int m = j + 1;
        float fk = f[k], fk1 = f[k + 1];
        double df = (double)fk1 - (double)fk;
        t = ph + P[n * LFRM + k]
              + (double)m * (double)fk * (1.0 / SRATE)
              + (double)(m * m) * df * (1.0 / (2.0 * SEGSZ * SRATE));
        float w  = ((float)j + 0.5f) * (1.0f / SEGSZ);
        float m0 = mb[k], m1 = mb[k + 1];
        mag = fmaf(w, m1 - m0, m0);
    }

    double frac = t - floor(t);                  // t mod 1 (revolutions)
    float s = __builtin_amdgcn_sinf((float)frac); // sin(2*pi*frac)
    out[(size_t)n * LWAVE + l] = s * mag;
}

// ---------------------------------------------------------------------------
extern "C" void kernel_launch(void* const* d_in, const int* in_sizes, int n_in,
                              void* d_out, int out_size, void* d_ws, size_t ws_size,
                              hipStream_t stream) {
    const float* x     = (const float*)d_in[0];
    const float* phi   = (const float*)d_in[1];
    const float* w_mag = (const float*)d_in[2];
    const float* b_mag = (const float*)d_in[3];
    const float* w_oct = (const float*)d_in[4];
    const float* b_oct = (const float*)d_in[5];
    float* out = (float*)d_out;

    int N = in_sizes[1];          // phi has N elements (N,1,1)

    char* ws = (char*)d_ws;
    float*  f0     = (float*)ws;                    // N*250*4
    float*  magbar = (float*)(ws + 64 * 1024);      // N*250*4
    double* P      = (double*)(ws + 128 * 1024);    // N*250*8

    k_frames<<<dim3(N, 4), 256, 0, stream>>>(x, w_mag, b_mag, w_oct, b_oct, f0, magbar);
    k_scan<<<N, 64, 0, stream>>>(f0, P);
    k_wave<<<dim3((LWAVE + 255) / 256, N), 256, 0, stream>>>(f0, magbar, P, phi, out);
}

// Round 2
// 22.669 us; speedup vs baseline: 1.4240x; 1.4240x over previous
//
#include <hip/hip_runtime.h>
#include <hip/hip_bf16.h>
#include <math.h>

#define SRATE 48000.0
#define SEGSZ 960
#define NHARM 8
#define LFRM 250
#define LWAVE (LFRM * SEGSZ)   // 240000
#define CCH 256

// ---------------------------------------------------------------------------
// Kernel 1: per-frame 1x1 convs -> f0[n][i], magbar[n][i] (= mean_h mag_h)
// block = 256 threads = 4 waves; each wave handles 64 channels, LDS-reduced.
// grid = (N, 4) ; i = blockIdx.y*64 + lane
// ---------------------------------------------------------------------------
__global__ __launch_bounds__(256) void k_frames(
        const float* __restrict__ x,
        const float* __restrict__ w_mag, const float* __restrict__ b_mag,
        const float* __restrict__ w_oct, const float* __restrict__ b_oct,
        float* __restrict__ f0, float* __restrict__ magbar) {
    __shared__ float sw[(NHARM + 1) * CCH];     // w_mag[8][256] then w_oct[256]
    __shared__ float sred[NHARM + 1][4][64];
    int tid  = threadIdx.x;
    int lane = tid & 63;
    int wv   = tid >> 6;
    for (int idx = tid; idx < NHARM * CCH; idx += 256) sw[idx] = w_mag[idx];
    for (int idx = tid; idx < CCH; idx += 256) sw[NHARM * CCH + idx] = w_oct[idx];
    __syncthreads();

    int n = blockIdx.x;
    int i = blockIdx.y * 64 + lane;
    bool act = (i < LFRM);
    int ii = act ? i : (LFRM - 1);
    const float* xp = x + (size_t)n * CCH * LFRM + ii;

    float oct = 0.f;
    float mh[NHARM];
#pragma unroll
    for (int h = 0; h < NHARM; ++h) mh[h] = 0.f;

    int c0 = wv * 64;
#pragma unroll 8
    for (int cc = 0; cc < 64; ++cc) {
        int c = c0 + cc;
        float xv = xp[c * LFRM];
        oct = fmaf(sw[NHARM * CCH + c], xv, oct);
#pragma unroll
        for (int h = 0; h < NHARM; ++h) mh[h] = fmaf(sw[h * CCH + c], xv, mh[h]);
    }
    sred[0][wv][lane] = oct;
#pragma unroll
    for (int h = 0; h < NHARM; ++h) sred[1 + h][wv][lane] = mh[h];
    __syncthreads();

    if (tid < 64 && act) {
        float o = sred[0][0][lane] + sred[0][1][lane] + sred[0][2][lane] + sred[0][3][lane];
        o += b_oct[0];
        float f0v = 220.0f * exp2f(o);
        float ms = 0.f;
#pragma unroll
        for (int h = 0; h < NHARM; ++h) {
            float mv = sred[1 + h][0][lane] + sred[1 + h][1][lane]
                     + sred[1 + h][2][lane] + sred[1 + h][3][lane];
            ms += expf(fminf(mv + b_mag[h], 6.0f));
        }
        f0[n * LFRM + i]     = f0v;
        magbar[n * LFRM + i] = ms * (1.0f / NHARM);
    }
}

// ---------------------------------------------------------------------------
// Kernel 2: per-batch prefix of region sums, in f64. One wave per n.
// S[k] = 480*(f0[k]+f0[k+1])/SR  (k=0..248)
// P[k] = head + sum_{k'<k} S[k'],  head = 480*f0[0]/SR,  k=0..249
// ---------------------------------------------------------------------------
__global__ __launch_bounds__(64) void k_scan(const float* __restrict__ f0,
                                             double* __restrict__ P) {
    int n = blockIdx.x;
    int lane = threadIdx.x;           // 0..63, lane owns k = 4*lane .. 4*lane+3
    const float* f = f0 + n * LFRM;

    double S[4];
    double local = 0.0;
#pragma unroll
    for (int m = 0; m < 4; ++m) {
        int k = 4 * lane + m;
        double s = 0.0;
        if (k < LFRM - 1)
            s = 480.0 * ((double)f[k] + (double)f[k + 1]) * (1.0 / SRATE);
        S[m] = s;
        local += s;
    }
    double incl = local;
    for (int off = 1; off < 64; off <<= 1) {
        double up = __shfl_up(incl, off, 64);
        if (lane >= off) incl += up;
    }
    double run = (incl - local) + 480.0 * (double)f[0] * (1.0 / SRATE);
#pragma unroll
    for (int m = 0; m < 4; ++m) {
        int k = 4 * lane + m;
        if (k < LFRM) P[n * LFRM + k] = run;
        run += S[m];
    }
}

// ---------------------------------------------------------------------------
// Kernel 3: region-aligned wave synthesis. grid = (250, N).
//   bx in [0,249): region k=bx, 960 samples starting at l = 480 + k*960.
//   bx == 249   : head (480 samples @ f0[0]) + tail (480 samples @ f0[249]).
// 240 active threads/block, 4 consecutive samples/thread, float4 store.
// One f64 fract(phi + P[k]) per thread; per-sample math is all f32:
//   t_rel(m) = m*fk/SR + m^2*df/(1920*SR),  m = j+1, j in [0,960)
//   relative phase <= ~13 revolutions -> f32 error ~1e-6 rev, negligible.
// ---------------------------------------------------------------------------
__global__ __launch_bounds__(256) void k_wave(
        const float* __restrict__ f0, const float* __restrict__ magbar,
        const double* __restrict__ P, const float* __restrict__ phi,
        float* __restrict__ out) {
    int tid = threadIdx.x;
    if (tid >= 240) return;
    int n  = blockIdx.y;
    int bx = blockIdx.x;

    const float* f  = f0 + n * LFRM;
    const float* mb = magbar + n * LFRM;
    double ph = (double)phi[n];

    float r[4];
    size_t l0;

    if (bx < LFRM - 1) {                       // full region k = bx
        int k = bx;
        float fk = f[k];
        float df = f[k + 1] - fk;
        float m0 = mb[k];
        float dm = mb[k + 1] - m0;
        double base = ph + P[n * LFRM + k];
        float bf = (float)(base - floor(base));
        float c1 = fk * (float)(1.0 / SRATE);
        float c2 = df * (float)(1.0 / (2.0 * SEGSZ * SRATE));
        int j0 = tid * 4;
        l0 = (size_t)(SEGSZ / 2) + (size_t)k * SEGSZ + j0;
#pragma unroll
        for (int q = 0; q < 4; ++q) {
            float mf = (float)(j0 + q + 1);
            float t  = fmaf(mf, c1, fmaf(mf * mf, c2, bf));
            float fr = t - floorf(t);
            float s  = __builtin_amdgcn_sinf(fr);     // sin(2*pi*fr)
            float w  = ((float)(j0 + q) + 0.5f) * (1.0f / SEGSZ);
            r[q] = s * fmaf(w, dm, m0);
        }
    } else {                                   // head + tail block
        bool tail = (tid >= 120);
        int k = tail ? (LFRM - 1) : 0;
        float fk = f[k];
        float mg = mb[k];
        double base = ph + (tail ? P[n * LFRM + (LFRM - 1)] : 0.0);
        float bf = (float)(base - floor(base));
        float c1 = fk * (float)(1.0 / SRATE);
        int j0 = (tail ? (tid - 120) : tid) * 4;
        l0 = (tail ? (size_t)(LWAVE - SEGSZ / 2) : 0) + j0;
#pragma unroll
        for (int q = 0; q < 4; ++q) {
            float mf = (float)(j0 + q + 1);
            float t  = fmaf(mf, c1, bf);
            float fr = t - floorf(t);
            r[q] = __builtin_amdgcn_sinf(fr) * mg;
        }
    }

    *reinterpret_cast<float4*>(out + (size_t)n * LWAVE + l0) =
        make_float4(r[0], r[1], r[2], r[3]);
}

// ---------------------------------------------------------------------------
extern "C" void kernel_launch(void* const* d_in, const int* in_sizes, int n_in,
                              void* d_out, int out_size, void* d_ws, size_t ws_size,
                              hipStream_t stream) {
    const float* x     = (const float*)d_in[0];
    const float* phi   = (const float*)d_in[1];
    const float* w_mag = (const float*)d_in[2];
    const float* b_mag = (const float*)d_in[3];
    const float* w_oct = (const float*)d_in[4];
    const float* b_oct = (const float*)d_in[5];
    float* out = (float*)d_out;

    int N = in_sizes[1];          // phi has N elements (N,1,1)

    char* ws = (char*)d_ws;
    float*  f0     = (float*)ws;                    // N*250*4
    float*  magbar = (float*)(ws + 64 * 1024);      // N*250*4
    double* P      = (double*)(ws + 128 * 1024);    // N*250*8

    k_frames<<<dim3(N, 4), 256, 0, stream>>>(x, w_mag, b_mag, w_oct, b_oct, f0, magbar);
    k_scan<<<N, 64, 0, stream>>>(f0, P);
    k_wave<<<dim3(LFRM, N), 256, 0, stream>>>(f0, magbar, P, phi, out);
}

// Round 3
// 20.871 us; speedup vs baseline: 1.5467x; 1.0861x over previous
//
#include <hip/hip_runtime.h>
#include <hip/hip_bf16.h>
#include <math.h>

#define SRATE 48000.0
#define SEGSZ 960
#define NHARM 8
#define LFRM 250
#define LWAVE (LFRM * SEGSZ)   // 240000
#define CCH 256
#define RPB 5                  // pseudo-regions per k_wave block (50*5 = 250)

// ---------------------------------------------------------------------------
// Kernel 1: per-frame 1x1 convs -> f0[n][i], magbar[n][i] (= mean_h mag_h)
// block = 256 threads = 4 waves; wave wv reduces channels [wv*64, wv*64+64),
// lane = frame index within the 64-frame strip. Weights are read with
// wave-uniform addresses -> scalar loads (SGPR broadcast), no LDS staging.
// grid = (N, 4)
// ---------------------------------------------------------------------------
__global__ __launch_bounds__(256) void k_frames(
        const float* __restrict__ x,
        const float* __restrict__ w_mag, const float* __restrict__ b_mag,
        const float* __restrict__ w_oct, const float* __restrict__ b_oct,
        float* __restrict__ f0, float* __restrict__ magbar) {
    __shared__ float sred[NHARM + 1][4][64];
    int tid  = threadIdx.x;
    int lane = tid & 63;
    int wv   = tid >> 6;

    int n = blockIdx.x;
    int i = blockIdx.y * 64 + lane;
    bool act = (i < LFRM);
    int ii = act ? i : (LFRM - 1);
    const float* xp = x + (size_t)n * CCH * LFRM + ii;

    float oct = 0.f;
    float mh[NHARM];
#pragma unroll
    for (int h = 0; h < NHARM; ++h) mh[h] = 0.f;

    int c0 = wv * 64;
#pragma unroll 8
    for (int cc = 0; cc < 64; ++cc) {
        int c = c0 + cc;                     // wave-uniform
        float xv = xp[(size_t)c * LFRM];
        oct = fmaf(w_oct[c], xv, oct);       // uniform addr -> s_load
#pragma unroll
        for (int h = 0; h < NHARM; ++h)
            mh[h] = fmaf(w_mag[h * CCH + c], xv, mh[h]);
    }
    sred[0][wv][lane] = oct;
#pragma unroll
    for (int h = 0; h < NHARM; ++h) sred[1 + h][wv][lane] = mh[h];
    __syncthreads();

    if (tid < 64 && act) {
        float o = sred[0][0][lane] + sred[0][1][lane] + sred[0][2][lane] + sred[0][3][lane];
        o += b_oct[0];
        float f0v = 220.0f * exp2f(o);
        float ms = 0.f;
#pragma unroll
        for (int h = 0; h < NHARM; ++h) {
            float mv = sred[1 + h][0][lane] + sred[1 + h][1][lane]
                     + sred[1 + h][2][lane] + sred[1 + h][3][lane];
            ms += expf(fminf(mv + b_mag[h], 6.0f));
        }
        f0[n * LFRM + i]     = f0v;
        magbar[n * LFRM + i] = ms * (1.0f / NHARM);
    }
}

// ---------------------------------------------------------------------------
// Kernel 2: fused scan + wave synthesis. grid = (50, N), block = 256.
// Block (g, n): stages f0[n][*], magbar[n][*] to LDS, wave 0 recomputes the
// 250-entry f64 phase prefix (P[k] = 480*f0[0]/SR + sum_{k'<k} S[k'],
// S[k] = 480*(f0[k]+f0[k+1])/SR), then 240 active threads synthesize
// pseudo-regions k = g*5 .. g*5+4 (k==249 -> head+tail), 1 float4 each.
// Per-sample math in f32 (relative phase <= ~13 rev; error ~1e-6 rev).
// ---------------------------------------------------------------------------
__global__ __launch_bounds__(256) void k_wave(
        const float* __restrict__ f0, const float* __restrict__ magbar,
        const float* __restrict__ phi, float* __restrict__ out) {
    __shared__ float  sf0[LFRM];
    __shared__ float  smb[LFRM];
    __shared__ double sP[LFRM];

    int tid = threadIdx.x;
    int n = blockIdx.y;
    int g = blockIdx.x;

    const float* f0g = f0 + n * LFRM;
    const float* mbg = magbar + n * LFRM;
    if (tid < LFRM) {
        sf0[tid] = f0g[tid];
        smb[tid] = mbg[tid];
    }
    __syncthreads();

    if (tid < 64) {                          // wave-0 f64 scan
        int lane = tid;
        double S[4];
        double local = 0.0;
#pragma unroll
        for (int m = 0; m < 4; ++m) {
            int k = 4 * lane + m;
            double s = 0.0;
            if (k < LFRM - 1)
                s = 480.0 * ((double)sf0[k] + (double)sf0[k + 1]) * (1.0 / SRATE);
            S[m] = s;
            local += s;
        }
        double incl = local;
        for (int off = 1; off < 64; off <<= 1) {
            double up = __shfl_up(incl, off, 64);
            if (lane >= off) incl += up;
        }
        double run = (incl - local) + 480.0 * (double)sf0[0] * (1.0 / SRATE);
#pragma unroll
        for (int m = 0; m < 4; ++m) {
            int k = 4 * lane + m;
            if (k < LFRM) sP[k] = run;
            run += S[m];
        }
    }
    __syncthreads();

    if (tid >= 240) return;
    double ph = (double)phi[n];
    int j0 = tid * 4;

#pragma unroll
    for (int r = 0; r < RPB; ++r) {
        int k = g * RPB + r;
        float rr[4];
        size_t l0;
        if (k < LFRM - 1) {                  // full region k
            float fk = sf0[k];
            float df = sf0[k + 1] - fk;
            float m0 = smb[k];
            float dm = smb[k + 1] - m0;
            double base = ph + sP[k];
            float bf = (float)(base - floor(base));
            float c1 = fk * (float)(1.0 / SRATE);
            float c2 = df * (float)(1.0 / (2.0 * SEGSZ * SRATE));
            l0 = (size_t)(SEGSZ / 2) + (size_t)k * SEGSZ + j0;
#pragma unroll
            for (int q = 0; q < 4; ++q) {
                float mf = (float)(j0 + q + 1);
                float t  = fmaf(mf, c1, fmaf(mf * mf, c2, bf));
                float fr = t - floorf(t);
                float s  = __builtin_amdgcn_sinf(fr);     // sin(2*pi*fr)
                float w  = ((float)(j0 + q) + 0.5f) * (1.0f / SEGSZ);
                rr[q] = s * fmaf(w, dm, m0);
            }
        } else {                             // head + tail (k == 249)
            bool tail = (tid >= 120);
            int kk = tail ? (LFRM - 1) : 0;
            float fk = sf0[kk];
            float mg = smb[kk];
            double base = ph + (tail ? sP[LFRM - 1] : 0.0);
            float bf = (float)(base - floor(base));
            float c1 = fk * (float)(1.0 / SRATE);
            int jl = (tail ? (tid - 120) : tid) * 4;
            l0 = (tail ? (size_t)(LWAVE - SEGSZ / 2) : 0) + jl;
#pragma unroll
            for (int q = 0; q < 4; ++q) {
                float mf = (float)(jl + q + 1);
                float t  = fmaf(mf, c1, bf);
                float fr = t - floorf(t);
                rr[q] = __builtin_amdgcn_sinf(fr) * mg;
            }
        }
        *reinterpret_cast<float4*>(out + (size_t)n * LWAVE + l0) =
            make_float4(rr[0], rr[1], rr[2], rr[3]);
    }
}

// ---------------------------------------------------------------------------
extern "C" void kernel_launch(void* const* d_in, const int* in_sizes, int n_in,
                              void* d_out, int out_size, void* d_ws, size_t ws_size,
                              hipStream_t stream) {
    const float* x     = (const float*)d_in[0];
    const float* phi   = (const float*)d_in[1];
    const float* w_mag = (const float*)d_in[2];
    const float* b_mag = (const float*)d_in[3];
    const float* w_oct = (const float*)d_in[4];
    const float* b_oct = (const float*)d_in[5];
    float* out = (float*)d_out;

    int N = in_sizes[1];          // phi has N elements (N,1,1)

    char* ws = (char*)d_ws;
    float* f0     = (float*)ws;                    // N*250*4
    float* magbar = (float*)(ws + 64 * 1024);      // N*250*4

    k_frames<<<dim3(N, 4), 256, 0, stream>>>(x, w_mag, b_mag, w_oct, b_oct, f0, magbar);
    k_wave<<<dim3(LFRM / RPB, N), 256, 0, stream>>>(f0, magbar, phi, out);
}